// Round 2
// baseline (465.599 us; speedup 1.0000x reference)
//
#include <hip/hip_runtime.h>
#include <math.h>

// Problem constants
#define B_N 8192
#define K_N 2048
#define D_N 768
#define R_N 32

// d_out element offsets: [x_q_st | loss | indices | dc]
#define OUT_XQ   0L
#define OUT_LOSS 6291456L
#define OUT_IDX  6291457L
#define OUT_DC   6299649L   // odd -> dc/P rows are 4B-aligned only; k==3 (mod 4) is 16B-aligned

// ---------------- emb = A @ B (f64 accumulate), h_k = ||e_k||^2  [bitwise == R4] ----------------
__global__ __launch_bounds__(256) void k_emb(const float* __restrict__ A,
                                             const float* __restrict__ Bm,
                                             float* __restrict__ emb,
                                             float* __restrict__ hf) {
    int k = blockIdx.x, t = threadIdx.x;
    __shared__ float a_s[R_N];
    if (t < R_N) a_s[t] = A[k * R_N + t];
    __syncthreads();
    double hpart = 0.0;
    for (int d = t; d < D_N; d += 256) {
        double e = 0.0;
#pragma unroll
        for (int r = 0; r < R_N; ++r) e += (double)a_s[r] * (double)Bm[r * D_N + d];
        float ef = (float)e;
        emb[(long)k * D_N + d] = ef;
        hpart += (double)ef * (double)ef;
    }
    __shared__ double red[256];
    red[t] = hpart; __syncthreads();
    for (int s = 128; s > 0; s >>= 1) { if (t < s) red[t] += red[t + s]; __syncthreads(); }
    if (t == 0) hf[k] = (float)red[0];
}

// ---------------- BT pack: BT4[i*32+r] = float4(B[r][4i..4i+3]) ----------------
__global__ __launch_bounds__(256) void k_btr(const float* __restrict__ Bm,
                                             float* __restrict__ BT) {
    int j = blockIdx.x * 256 + threadIdx.x;   // 192*32*4 = 24576 floats
    int i = j >> 7;                           // float4 index 0..191
    int rc = j & 127;
    int r = rc >> 2, c = rc & 3;
    BT[j] = Bm[r * D_N + 4 * i + c];
}

// ---------------- y = x @ B^T [bitwise == R4] + fused ||x_b||^2 (f64) ----------------
// R2 rework: latency-bound fix on both axes.
//   TLP: 8 rows/block -> 1024 blocks = 4 blocks/CU = 16 waves/CU (was 2 blocks/CU).
//   ILP: explicit 6-deep double-buffered pipeline (A/B reg buffers, static indexing)
//        keeps 12 float4 loads in flight under the previous stage's 24 FMAs.
// Per-row FMA chain order (i ascending, x,y,z,w) and the normred reduction order are
// IDENTICAL to R4 -> y and A64 bitwise unchanged.
#define PF 6
__global__ __launch_bounds__(256, 4) void k_ygemm(const float* __restrict__ x,
                                                  const float* __restrict__ BT,
                                                  float* __restrict__ y,
                                                  double* __restrict__ A64) {
    __shared__ double normred[8][32];
    int t = threadIdx.x;
    int b0 = blockIdx.x * 8;
    int b = t >> 5, r = t & 31;
    const float4* BT4 = (const float4*)BT;
    const float4* X4 = (const float4*)(x + (long)(b0 + b) * D_N);
    float4 acc = make_float4(0.f, 0.f, 0.f, 0.f);

    float4 bA[PF], xA[PF], bB[PF], xB[PF];
#pragma unroll
    for (int j = 0; j < PF; ++j) { bA[j] = BT4[j * 32 + r]; xA[j] = X4[j]; }
    int base = PF;
#pragma unroll 1
    for (int s = 0; s < 15; ++s) {
        // prefetch stage 2s+1 into B, compute stage 2s from A
#pragma unroll
        for (int j = 0; j < PF; ++j) { bB[j] = BT4[(base + j) * 32 + r]; xB[j] = X4[base + j]; }
#pragma unroll
        for (int j = 0; j < PF; ++j) {
            acc.x = fmaf(xA[j].x, bA[j].x, acc.x);
            acc.y = fmaf(xA[j].y, bA[j].y, acc.y);
            acc.z = fmaf(xA[j].z, bA[j].z, acc.z);
            acc.w = fmaf(xA[j].w, bA[j].w, acc.w);
        }
        base += PF;
        // prefetch stage 2s+2 into A, compute stage 2s+1 from B
#pragma unroll
        for (int j = 0; j < PF; ++j) { bA[j] = BT4[(base + j) * 32 + r]; xA[j] = X4[base + j]; }
#pragma unroll
        for (int j = 0; j < PF; ++j) {
            acc.x = fmaf(xB[j].x, bB[j].x, acc.x);
            acc.y = fmaf(xB[j].y, bB[j].y, acc.y);
            acc.z = fmaf(xB[j].z, bB[j].z, acc.z);
            acc.w = fmaf(xB[j].w, bB[j].w, acc.w);
        }
        base += PF;
    }
    // base == 186: load stage 31 into B, compute stage 30 (A), then stage 31 (B)
#pragma unroll
    for (int j = 0; j < PF; ++j) { bB[j] = BT4[(base + j) * 32 + r]; xB[j] = X4[base + j]; }
#pragma unroll
    for (int j = 0; j < PF; ++j) {
        acc.x = fmaf(xA[j].x, bA[j].x, acc.x);
        acc.y = fmaf(xA[j].y, bA[j].y, acc.y);
        acc.z = fmaf(xA[j].z, bA[j].z, acc.z);
        acc.w = fmaf(xA[j].w, bA[j].w, acc.w);
    }
#pragma unroll
    for (int j = 0; j < PF; ++j) {
        acc.x = fmaf(xB[j].x, bB[j].x, acc.x);
        acc.y = fmaf(xB[j].y, bB[j].y, acc.y);
        acc.z = fmaf(xB[j].z, bB[j].z, acc.z);
        acc.w = fmaf(xB[j].w, bB[j].w, acc.w);
    }
    y[(long)(b0 + b) * R_N + r] = (acc.x + acc.y) + (acc.z + acc.w);

    // xnorm partials: thread (b,r) sums d = r + 32*q, q ascending (same chain as R4).
    // Coalesced 128B per row; rows are L1/L2-hot (just streamed by this wave).
    const float* xr = x + (long)(b0 + b) * D_N + r;
    double nv = 0.0;
#pragma unroll
    for (int q = 0; q < 24; ++q) {
        double v = (double)xr[32 * q];
        nv += v * v;
    }
    normred[b][r] = nv;
    __syncthreads();
    if (t < 8) {
        double s = 0.0;
#pragma unroll
        for (int r2 = 0; r2 < 32; ++r2) s += normred[t][r2];
        A64[b0 + t] = s;
    }
}

// ---------------- P[b,k] = h_k - 2 y_b.A_k + fused min/max partials  [bitwise == R4] ----------------
__global__ __launch_bounds__(256) void k_pgemm(const float* __restrict__ Am,
                                               const float* __restrict__ y,
                                               const float* __restrict__ hf,
                                               const double* __restrict__ A64,
                                               float* __restrict__ P,
                                               double* __restrict__ mmpart) {
    __shared__ float As[256][33];
    __shared__ float ys[32][32];
    __shared__ double a64s[32];
    __shared__ double smn[256], smx[256];
    int t = threadIdx.x;
    int k0 = blockIdx.x * 256, b0 = blockIdx.y * 32;
    for (int i = t; i < 256 * 32; i += 256) As[i >> 5][i & 31] = Am[(long)(k0 + (i >> 5)) * R_N + (i & 31)];
    for (int i = t; i < 32 * 32; i += 256) ys[i >> 5][i & 31] = y[(long)(b0 + (i >> 5)) * R_N + (i & 31)];
    if (t < 32) a64s[t] = A64[b0 + t];
    __syncthreads();
    int k = k0 + t;
    float ar[32];
#pragma unroll
    for (int r = 0; r < 32; ++r) ar[r] = As[t][r];
    float hk = hf[k];
    double mn = 1e300, mx = -1e300;
#pragma unroll 4
    for (int b = 0; b < 32; ++b) {
        float dot = 0.f;
#pragma unroll
        for (int r = 0; r < 32; ++r) dot = fmaf(ys[b][r], ar[r], dot);
        float p = fmaf(-2.f, dot, hk);
        P[(long)(b0 + b) * K_N + k] = p;
        double dv = a64s[b] + (double)p;
        mn = fmin(mn, dv); mx = fmax(mx, dv);
    }
    smn[t] = mn; smx[t] = mx; __syncthreads();
    for (int s = 128; s > 0; s >>= 1) {
        if (t < s) { smn[t] = fmin(smn[t], smn[t + s]); smx[t] = fmax(smx[t], smx[t + s]); }
        __syncthreads();
    }
    if (t == 0) {
        int bid = blockIdx.y * gridDim.x + blockIdx.x;
        mmpart[2 * bid] = smn[0]; mmpart[2 * bid + 1] = smx[0];
    }
}

// ---------------- minmax reduce -> sc, fused gamma init  [== R4] ----------------
__global__ __launch_bounds__(256) void k_minmax2(const double* __restrict__ part,
                                                 double* __restrict__ sc,
                                                 const double* __restrict__ A64,
                                                 float* __restrict__ gammaf, int nblk) {
    int t = threadIdx.x;
    double mn = 1e300, mx = -1e300;
    for (int i = t; i < nblk; i += 256) {
        mn = fmin(mn, part[2 * i]); mx = fmax(mx, part[2 * i + 1]);
    }
    __shared__ double smn[256], smx[256];
    __shared__ double ssc[4];
    smn[t] = mn; smx[t] = mx; __syncthreads();
    for (int s = 128; s > 0; s >>= 1) {
        if (t < s) { smn[t] = fmin(smn[t], smn[t + s]); smx[t] = fmax(smx[t], smx[t + s]); }
        __syncthreads();
    }
    if (t == 0) {
        double mid = (smx[0] + smn[0]) * 0.5;
        double ampl = smx[0] - mid + 1e-5;
        sc[0] = ssc[0] = mid; sc[1] = ssc[1] = ampl; sc[2] = ssc[2] = smn[0];
        sc[3] = ssc[3] = 1.0 / (0.01 * ampl);   // beta
    }
    __syncthreads();
    double bet = ssc[3], mnv = ssc[2];
    for (int i = t; i < B_N; i += 256)
        gammaf[i] = (float)(bet * (mnv - A64[i]));
}

// ---------------- first colsum (c0)  [bitwise == R4] ----------------
__global__ __launch_bounds__(256) void k_colsum(const float* __restrict__ P,
                                                const float* __restrict__ gammaf,
                                                const double* __restrict__ sc,
                                                float* __restrict__ part) {
    __shared__ float gs[64];
    int t = threadIdx.x;
    int k = blockIdx.x * 256 + t;
    int b0 = blockIdx.y * 64;
    if (t < 64) gs[t] = gammaf[b0 + t];
    __syncthreads();
    float betaf = (float)sc[3];
    float s0 = 0.f, s1 = 0.f, s2 = 0.f, s3 = 0.f;
#pragma unroll
    for (int j = 0; j < 64; j += 4) {
        s0 += __expf(gs[j]     - betaf * P[(long)(b0 + j)     * K_N + k]);
        s1 += __expf(gs[j + 1] - betaf * P[(long)(b0 + j + 1) * K_N + k]);
        s2 += __expf(gs[j + 2] - betaf * P[(long)(b0 + j + 2) * K_N + k]);
        s3 += __expf(gs[j + 3] - betaf * P[(long)(b0 + j + 3) * K_N + k]);
    }
    part[(long)blockIdx.y * K_N + k] = (s0 + s1) + (s2 + s3);
}

__global__ __launch_bounds__(256) void k_colsum2(const float* __restrict__ part,
                                                 double* __restrict__ lnr64,
                                                 float* __restrict__ lnrf) {
    int k = blockIdx.x * 256 + threadIdx.x;
    double s = 0.0;
#pragma unroll 4
    for (int c = 0; c < 128; ++c) s += (double)part[(long)c * K_N + k];
    double l = -log(s);
    lnr64[k] = l; lnrf[k] = (float)l;
}

// ---------------- fused rowsum_i + colsum_{i+1}: ONE pass over P ----------------
__global__ __launch_bounds__(512) void k_fused(const float* __restrict__ P,
                                               const float* __restrict__ lnrf,
                                               const double* __restrict__ sc,
                                               float* __restrict__ part) {
    __shared__ double wred[8];
    int t = threadIdx.x, l = t & 63, w = t >> 6;
    float betaf = (float)sc[3];
    int kbase = 3 + 4 * t;
    float ln0, ln1, ln2, ln3;
    if (t < 511) { ln0 = lnrf[kbase]; ln1 = lnrf[kbase + 1]; ln2 = lnrf[kbase + 2]; ln3 = lnrf[kbase + 3]; }
    else         { ln0 = lnrf[0];     ln1 = lnrf[1];         ln2 = lnrf[2];         ln3 = lnrf[2047]; }
    float4 acc = make_float4(0.f, 0.f, 0.f, 0.f);
    long rowbase = (long)blockIdx.x * 16;
    for (int rr = 0; rr < 16; ++rr) {
        const float* row = P + (rowbase + rr) * K_N;
        float p0, p1, p2, p3;
        if (t < 511) {
            float4 p4 = *(const float4*)(row + kbase);
            p0 = p4.x; p1 = p4.y; p2 = p4.z; p3 = p4.w;
        } else {
            p0 = row[0]; p1 = row[1]; p2 = row[2]; p3 = row[2047];
        }
        float e0 = __expf(ln0 - betaf * p0);
        float e1 = __expf(ln1 - betaf * p1);
        float e2 = __expf(ln2 - betaf * p2);
        float e3 = __expf(ln3 - betaf * p3);
        double s = (double)((e0 + e1) + (e2 + e3));
#pragma unroll
        for (int off = 1; off < 64; off <<= 1) s += __shfl_xor(s, off, 64);
        if (l == 0) wred[w] = s;
        __syncthreads();
        double ss = ((wred[0] + wred[1]) + (wred[2] + wred[3]))
                  + ((wred[4] + wred[5]) + (wred[6] + wred[7]));
        float gf = (float)(-log(ss));
        __syncthreads();
        acc.x += __expf(gf - betaf * p0);
        acc.y += __expf(gf - betaf * p1);
        acc.z += __expf(gf - betaf * p2);
        acc.w += __expf(gf - betaf * p3);
    }
    // slot layout: t<511 -> slots 4t..4t+3 (k=3+4t..); t=511 -> slots 2044..2047 (k=0,1,2,2047)
    ((float4*)(part + (long)blockIdx.x * K_N))[t] = acc;
}

// reduce fused partials -> lnr (wave per k, deterministic)
__global__ __launch_bounds__(512) void k_freduce(const float* __restrict__ part,
                                                 double* __restrict__ lnr64,
                                                 float* __restrict__ lnrf) {
    int t = threadIdx.x, l = t & 63, w = t >> 6;
    int k = blockIdx.x * 8 + w;
    int slot = (k >= 3 && k < 2047) ? (k - 3) : (k < 3 ? 2044 + k : 2047);
    double s = 0.0;
#pragma unroll
    for (int j = 0; j < 8; ++j)
        s += (double)part[(long)(l + 64 * j) * K_N + slot];
#pragma unroll
    for (int off = 1; off < 64; off <<= 1) s += __shfl_xor(s, off, 64);
    if (l == 0) { double v = -log(s); lnr64[k] = v; lnrf[k] = (float)v; }
}

// ---------------- final: wave per row — hoisted loads, argmax(f64), dc in place,
// loss via ||e-x||^2 = A64[b] + P[b,bi] (P recovered from dec), gather emb ----------------
__global__ __launch_bounds__(512) void k_final(const double* __restrict__ lnr64,
                                               const double* __restrict__ sc,
                                               const double* __restrict__ A64,
                                               const float* __restrict__ emb,
                                               float* __restrict__ out,
                                               double* __restrict__ lossp) {
    int t = threadIdx.x, l = t & 63, w = t >> 6;
    long b = (long)blockIdx.x * 8 + w;
    float* row = out + OUT_DC + b * K_N;     // P in, dc out (disjoint per wave)
    double beta = sc[3], mid = sc[0], inva = 1.0 / sc[1];
    double a64b = A64[b];
    // ---- hoist ALL loads before any store (avoid alias serialization) ----
    float pe = 0.f;
    if (l < 3)   pe = row[l];
    if (l == 63) pe = row[2047];
    float4 pv[8];
#pragma unroll
    for (int c = 0; c < 8; ++c) {
        int i = l + 64 * c;
        if (i < 511) pv[c] = *(const float4*)(row + 3 + 4 * i);
    }
    // ---- argmax (in-lane ascending k -> first-max) + dc stores ----
    double best = -1e300; int bi = 1 << 30;
    if (l < 3) {
        double p = (double)pe;
        double dec = lnr64[l] - beta * p;
        if (dec > best) { best = dec; bi = l; }
        row[l] = (float)((a64b + p - mid) * inva);
    }
#pragma unroll
    for (int c = 0; c < 8; ++c) {
        int i = l + 64 * c;
        if (i < 511) {
            int k = 3 + 4 * i;
            double p0 = pv[c].x, p1 = pv[c].y, p2 = pv[c].z, p3 = pv[c].w;
            double d0 = lnr64[k] - beta * p0;
            double d1 = lnr64[k + 1] - beta * p1;
            double d2 = lnr64[k + 2] - beta * p2;
            double d3 = lnr64[k + 3] - beta * p3;
            if (d0 > best) { best = d0; bi = k; }
            if (d1 > best) { best = d1; bi = k + 1; }
            if (d2 > best) { best = d2; bi = k + 2; }
            if (d3 > best) { best = d3; bi = k + 3; }
            float4 dcv;
            dcv.x = (float)((a64b + p0 - mid) * inva);
            dcv.y = (float)((a64b + p1 - mid) * inva);
            dcv.z = (float)((a64b + p2 - mid) * inva);
            dcv.w = (float)((a64b + p3 - mid) * inva);
            *(float4*)(row + k) = dcv;
        }
    }
    if (l == 63) {
        double p = (double)pe;
        double dec = lnr64[2047] - beta * p;
        if (dec > best) { best = dec; bi = 2047; }
        row[2047] = (float)((a64b + p - mid) * inva);
    }
#pragma unroll
    for (int off = 1; off < 64; off <<= 1) {                   // first-max: min idx on ties
        double ov = __shfl_xor(best, off, 64);
        int oi = __shfl_xor(bi, off, 64);
        if (ov > best || (ov == best && oi < bi)) { best = ov; bi = oi; }
    }
    if (l == 0) {
        out[OUT_IDX + b] = (float)bi;
        // ||e_bi - x_b||^2 = A64[b] + P[b,bi]; P recovered: dec = lnr - beta*P
        double prec = (lnr64[bi] - best) / beta;
        lossp[b] = a64b + prec;
    }
    // gather emb -> x_q
    const float4* E4 = (const float4*)(emb + (long)bi * D_N);
    float4* O4 = (float4*)(out + OUT_XQ + b * D_N);
#pragma unroll
    for (int i = 0; i < 3; ++i) O4[i * 64 + l] = E4[i * 64 + l];
}

__global__ __launch_bounds__(1024) void k_loss2(const double* __restrict__ lossp,
                                                float* __restrict__ out) {
    __shared__ double red[1024];
    int t = threadIdx.x;
    double s = 0.0;
#pragma unroll
    for (int j = 0; j < 8; ++j) s += lossp[t + 1024 * j];
    red[t] = s; __syncthreads();
    for (int st = 512; st > 0; st >>= 1) { if (t < st) red[t] += red[t + st]; __syncthreads(); }
    if (t == 0) out[OUT_LOSS] = (float)(red[0] * 1.25 / (double)((long)B_N * D_N));
}

extern "C" void kernel_launch(void* const* d_in, const int* in_sizes, int n_in,
                              void* d_out, int out_size, void* d_ws, size_t ws_size,
                              hipStream_t stream) {
    const float* x  = (const float*)d_in[0];   // [8192,768]
    const float* Am = (const float*)d_in[1];   // [2048,32]
    const float* Bm = (const float*)d_in[2];   // [32,768]
    float* out = (float*)d_out;
    float* P = out + OUT_DC;                   // P lives in dc region; k_final converts in place

    char* ws = (char*)d_ws;
    float*  emb     = (float*)(ws);                 // 6,291,456 B
    // 4 MB pool at +6291456: y (1 MB, dead after pgemm) | cs_part (1 MB, dead after c0's
    // colsum2) | 2 MB spare — reused as fpart [512][2048] f32 by k_fused/k_freduce.
    // BT (96 KB) overlays the cs_part region: written by k_btr, dead after k_ygemm,
    // long before k_colsum first writes cs_part.
    float*  y       = (float*)(ws + 6291456);       // 1,048,576 B
    float*  cs_part = (float*)(ws + 7340032);       // 128*2048*4 = 1,048,576 B
    float*  BTg     = (float*)(ws + 7340032);       // 98,304 B (overlays cs_part)
    float*  fpart   = (float*)(ws + 6291456);       // 512*2048*4 = 4,194,304 B (overlays y+cs_part)
    double* A64     = (double*)(ws + 10485760);     // 65,536 B
    float*  hf      = (float*)(ws + 10551296);      // 8,192 B
    float*  gammaf  = (float*)(ws + 10559488);      // 32,768 B
    double* lnr64   = (double*)(ws + 10592256);     // 16,384 B
    float*  lnrf    = (float*)(ws + 10608640);      // 8,192 B
    double* mmpart  = (double*)(ws + 10616832);     // 2048*2*8 = 32,768 B
    double* sc      = (double*)(ws + 10649600);     // 4 doubles
    double* lossp   = (double*)(ws + 10649856);     // 8192*8 = 65,536 B
    // total ws use ~10.7 MB

    k_btr<<<96, 256, 0, stream>>>(Bm, BTg);
    k_emb<<<K_N, 256, 0, stream>>>(Am, Bm, emb, hf);
    k_ygemm<<<B_N / 8, 256, 0, stream>>>(x, BTg, y, A64);

    dim3 gp(K_N / 256, B_N / 32);
    k_pgemm<<<gp, 256, 0, stream>>>(Am, y, hf, A64, P, mmpart);
    k_minmax2<<<1, 256, 0, stream>>>(mmpart, sc, A64, gammaf, 2048);

    // c0 (colsum with gamma0), then 5 fused (rowsum_i + colsum_{i+1}) passes:
    // total colsum x6 / rowsum x5 == R4's schedule; contraction ~0.022/cycle,
    // residual ~2e-10 << ~1e-6 decision gap.
    dim3 ga(K_N / 256, 128);
    k_colsum<<<ga, 256, 0, stream>>>(P, gammaf, sc, cs_part);
    k_colsum2<<<K_N / 256, 256, 0, stream>>>(cs_part, lnr64, lnrf);
    for (int it = 0; it < 5; ++it) {
        k_fused<<<512, 512, 0, stream>>>(P, lnrf, sc, fpart);
        k_freduce<<<256, 512, 0, stream>>>(fpart, lnr64, lnrf);
    }

    k_final<<<B_N / 8, 512, 0, stream>>>(lnr64, sc, A64, emb, out, lossp);
    k_loss2<<<1, 1024, 0, stream>>>(lossp, out);
}

// Round 3
// 462.074 us; speedup vs baseline: 1.0076x; 1.0076x over previous
//
#include <hip/hip_runtime.h>
#include <math.h>

// Problem constants
#define B_N 8192
#define K_N 2048
#define D_N 768
#define R_N 32

// d_out element offsets: [x_q_st | loss | indices | dc]
#define OUT_XQ   0L
#define OUT_LOSS 6291456L
#define OUT_IDX  6291457L
#define OUT_DC   6299649L   // odd -> dc/P rows are 4B-aligned only; k==3 (mod 4) is 16B-aligned

// ---------------- emb = A @ B (f64 accumulate), h_k = ||e_k||^2  [bitwise == R4] ----------------
__global__ __launch_bounds__(256) void k_emb(const float* __restrict__ A,
                                             const float* __restrict__ Bm,
                                             float* __restrict__ emb,
                                             float* __restrict__ hf) {
    int k = blockIdx.x, t = threadIdx.x;
    __shared__ float a_s[R_N];
    if (t < R_N) a_s[t] = A[k * R_N + t];
    __syncthreads();
    double hpart = 0.0;
    for (int d = t; d < D_N; d += 256) {
        double e = 0.0;
#pragma unroll
        for (int r = 0; r < R_N; ++r) e += (double)a_s[r] * (double)Bm[r * D_N + d];
        float ef = (float)e;
        emb[(long)k * D_N + d] = ef;
        hpart += (double)ef * (double)ef;
    }
    __shared__ double red[256];
    red[t] = hpart; __syncthreads();
    for (int s = 128; s > 0; s >>= 1) { if (t < s) red[t] += red[t + s]; __syncthreads(); }
    if (t == 0) hf[k] = (float)red[0];
}

// ---------------- BT pack: BT4[i*32+r] = float4(B[r][4i..4i+3]) ----------------
__global__ __launch_bounds__(256) void k_btr(const float* __restrict__ Bm,
                                             float* __restrict__ BT) {
    int j = blockIdx.x * 256 + threadIdx.x;   // 192*32*4 = 24576 floats
    int i = j >> 7;                           // float4 index 0..191
    int rc = j & 127;
    int r = rc >> 2, c = rc & 3;
    BT[j] = Bm[r * D_N + 4 * i + c];
}

// ---------------- y = x @ B^T [bitwise == R4] + fused ||x_b||^2 (f64) ----------------
// R3 rework:
//   x: staged to LDS via async global_load_lds (16B/lane, contiguous 24KB tile).
//      Inner loop reads x as ds_read_b128 broadcast; xnorm re-read also from LDS
//      (identical bits -> A64 bitwise unchanged). x touches HBM exactly once, wide.
//   B: packed BT from L2, 2-buffer register pipeline PINNED with sched_barrier(0)
//      fences so the compiler cannot sink the prefetch group into the consume group
//      (R2 failure mode: VGPR=64 proved the pipeline was collapsed).
// Per-row FMA chain order (i ascending, x,y,z,w) IDENTICAL to R4 -> y bitwise unchanged.
__global__ __launch_bounds__(256, 4) void k_ygemm(const float* __restrict__ x,
                                                  const float* __restrict__ BT,
                                                  float* __restrict__ y,
                                                  double* __restrict__ A64) {
    __shared__ __align__(16) float xs[8 * D_N];     // 24 KB
    __shared__ double normred[8][32];
    int t = threadIdx.x;
    long b0 = (long)blockIdx.x * 8;

    // ---- stage x tile (contiguous 24 KB) global->LDS, 16B per thread per step ----
    const float* xsrc = x + b0 * D_N;
#pragma unroll
    for (int j = 0; j < 6; ++j) {
        __builtin_amdgcn_global_load_lds(
            (const __attribute__((address_space(1))) void*)(xsrc + j * 1024 + t * 4),
            (__attribute__((address_space(3))) void*)(xs + j * 1024 + t * 4),
            16, 0, 0);
    }
    __syncthreads();   // drains vmcnt before any LDS read

    int b = t >> 5, r = t & 31;
    const float4* BT4 = (const float4*)BT;
    const float4* XL = (const float4*)(xs + b * D_N);   // LDS, broadcast per half-wave
    float4 acc = make_float4(0.f, 0.f, 0.f, 0.f);

    float4 bA[8], bB[8];
#define LOADG(buf, gi)                                                    \
    _Pragma("unroll")                                                     \
    for (int j = 0; j < 8; ++j) buf[j] = BT4[((gi) * 8 + j) * 32 + r];
#define COMPG(buf, gi)                                                    \
    _Pragma("unroll")                                                     \
    for (int j = 0; j < 8; ++j) {                                         \
        float4 xv = XL[(gi) * 8 + j];                                     \
        acc.x = fmaf(xv.x, buf[j].x, acc.x);                              \
        acc.y = fmaf(xv.y, buf[j].y, acc.y);                              \
        acc.z = fmaf(xv.z, buf[j].z, acc.z);                              \
        acc.w = fmaf(xv.w, buf[j].w, acc.w);                              \
    }

    LOADG(bA, 0)
#pragma unroll 1
    for (int g = 0; g < 11; ++g) {
        LOADG(bB, 2 * g + 1)
        __builtin_amdgcn_sched_barrier(0);
        COMPG(bA, 2 * g)
        __builtin_amdgcn_sched_barrier(0);
        LOADG(bA, 2 * g + 2)
        __builtin_amdgcn_sched_barrier(0);
        COMPG(bB, 2 * g + 1)
        __builtin_amdgcn_sched_barrier(0);
    }
    // epilogue: groups 22 (in bA) and 23
    LOADG(bB, 23)
    __builtin_amdgcn_sched_barrier(0);
    COMPG(bA, 22)
    __builtin_amdgcn_sched_barrier(0);
    COMPG(bB, 23)
#undef LOADG
#undef COMPG

    y[(long)(b0 + b) * R_N + r] = (acc.x + acc.y) + (acc.z + acc.w);

    // xnorm partials from LDS (same bits as global x): thread (b,r) sums d = r+32q,
    // q ascending — chain order IDENTICAL to R4.
    const float* xr = xs + b * D_N + r;
    double nv = 0.0;
#pragma unroll
    for (int q = 0; q < 24; ++q) {
        double v = (double)xr[32 * q];
        nv += v * v;
    }
    normred[b][r] = nv;
    __syncthreads();
    if (t < 8) {
        double s = 0.0;
#pragma unroll
        for (int r2 = 0; r2 < 32; ++r2) s += normred[t][r2];
        A64[b0 + t] = s;
    }
}

// ---------------- P[b,k] = h_k - 2 y_b.A_k + fused min/max partials  [bitwise == R4] ----------------
__global__ __launch_bounds__(256) void k_pgemm(const float* __restrict__ Am,
                                               const float* __restrict__ y,
                                               const float* __restrict__ hf,
                                               const double* __restrict__ A64,
                                               float* __restrict__ P,
                                               double* __restrict__ mmpart) {
    __shared__ float As[256][33];
    __shared__ float ys[32][32];
    __shared__ double a64s[32];
    __shared__ double smn[256], smx[256];
    int t = threadIdx.x;
    int k0 = blockIdx.x * 256, b0 = blockIdx.y * 32;
    for (int i = t; i < 256 * 32; i += 256) As[i >> 5][i & 31] = Am[(long)(k0 + (i >> 5)) * R_N + (i & 31)];
    for (int i = t; i < 32 * 32; i += 256) ys[i >> 5][i & 31] = y[(long)(b0 + (i >> 5)) * R_N + (i & 31)];
    if (t < 32) a64s[t] = A64[b0 + t];
    __syncthreads();
    int k = k0 + t;
    float ar[32];
#pragma unroll
    for (int r = 0; r < 32; ++r) ar[r] = As[t][r];
    float hk = hf[k];
    double mn = 1e300, mx = -1e300;
#pragma unroll 4
    for (int b = 0; b < 32; ++b) {
        float dot = 0.f;
#pragma unroll
        for (int r = 0; r < 32; ++r) dot = fmaf(ys[b][r], ar[r], dot);
        float p = fmaf(-2.f, dot, hk);
        P[(long)(b0 + b) * K_N + k] = p;
        double dv = a64s[b] + (double)p;
        mn = fmin(mn, dv); mx = fmax(mx, dv);
    }
    smn[t] = mn; smx[t] = mx; __syncthreads();
    for (int s = 128; s > 0; s >>= 1) {
        if (t < s) { smn[t] = fmin(smn[t], smn[t + s]); smx[t] = fmax(smx[t], smx[t + s]); }
        __syncthreads();
    }
    if (t == 0) {
        int bid = blockIdx.y * gridDim.x + blockIdx.x;
        mmpart[2 * bid] = smn[0]; mmpart[2 * bid + 1] = smx[0];
    }
}

// ---------------- minmax reduce -> sc, fused gamma init  [== R4] ----------------
__global__ __launch_bounds__(256) void k_minmax2(const double* __restrict__ part,
                                                 double* __restrict__ sc,
                                                 const double* __restrict__ A64,
                                                 float* __restrict__ gammaf, int nblk) {
    int t = threadIdx.x;
    double mn = 1e300, mx = -1e300;
    for (int i = t; i < nblk; i += 256) {
        mn = fmin(mn, part[2 * i]); mx = fmax(mx, part[2 * i + 1]);
    }
    __shared__ double smn[256], smx[256];
    __shared__ double ssc[4];
    smn[t] = mn; smx[t] = mx; __syncthreads();
    for (int s = 128; s > 0; s >>= 1) {
        if (t < s) { smn[t] = fmin(smn[t], smn[t + s]); smx[t] = fmax(smx[t], smx[t + s]); }
        __syncthreads();
    }
    if (t == 0) {
        double mid = (smx[0] + smn[0]) * 0.5;
        double ampl = smx[0] - mid + 1e-5;
        sc[0] = ssc[0] = mid; sc[1] = ssc[1] = ampl; sc[2] = ssc[2] = smn[0];
        sc[3] = ssc[3] = 1.0 / (0.01 * ampl);   // beta
    }
    __syncthreads();
    double bet = ssc[3], mnv = ssc[2];
    for (int i = t; i < B_N; i += 256)
        gammaf[i] = (float)(bet * (mnv - A64[i]));
}

// ---------------- first colsum (c0)  [bitwise == R4] ----------------
__global__ __launch_bounds__(256) void k_colsum(const float* __restrict__ P,
                                                const float* __restrict__ gammaf,
                                                const double* __restrict__ sc,
                                                float* __restrict__ part) {
    __shared__ float gs[64];
    int t = threadIdx.x;
    int k = blockIdx.x * 256 + t;
    int b0 = blockIdx.y * 64;
    if (t < 64) gs[t] = gammaf[b0 + t];
    __syncthreads();
    float betaf = (float)sc[3];
    float s0 = 0.f, s1 = 0.f, s2 = 0.f, s3 = 0.f;
#pragma unroll
    for (int j = 0; j < 64; j += 4) {
        s0 += __expf(gs[j]     - betaf * P[(long)(b0 + j)     * K_N + k]);
        s1 += __expf(gs[j + 1] - betaf * P[(long)(b0 + j + 1) * K_N + k]);
        s2 += __expf(gs[j + 2] - betaf * P[(long)(b0 + j + 2) * K_N + k]);
        s3 += __expf(gs[j + 3] - betaf * P[(long)(b0 + j + 3) * K_N + k]);
    }
    part[(long)blockIdx.y * K_N + k] = (s0 + s1) + (s2 + s3);
}

__global__ __launch_bounds__(256) void k_colsum2(const float* __restrict__ part,
                                                 double* __restrict__ lnr64,
                                                 float* __restrict__ lnrf) {
    int k = blockIdx.x * 256 + threadIdx.x;
    double s = 0.0;
#pragma unroll 4
    for (int c = 0; c < 128; ++c) s += (double)part[(long)c * K_N + k];
    double l = -log(s);
    lnr64[k] = l; lnrf[k] = (float)l;
}

// ---------------- fused rowsum_i + colsum_{i+1}: ONE pass over P ----------------
__global__ __launch_bounds__(512) void k_fused(const float* __restrict__ P,
                                               const float* __restrict__ lnrf,
                                               const double* __restrict__ sc,
                                               float* __restrict__ part) {
    __shared__ double wred[8];
    int t = threadIdx.x, l = t & 63, w = t >> 6;
    float betaf = (float)sc[3];
    int kbase = 3 + 4 * t;
    float ln0, ln1, ln2, ln3;
    if (t < 511) { ln0 = lnrf[kbase]; ln1 = lnrf[kbase + 1]; ln2 = lnrf[kbase + 2]; ln3 = lnrf[kbase + 3]; }
    else         { ln0 = lnrf[0];     ln1 = lnrf[1];         ln2 = lnrf[2];         ln3 = lnrf[2047]; }
    float4 acc = make_float4(0.f, 0.f, 0.f, 0.f);
    long rowbase = (long)blockIdx.x * 16;
    for (int rr = 0; rr < 16; ++rr) {
        const float* row = P + (rowbase + rr) * K_N;
        float p0, p1, p2, p3;
        if (t < 511) {
            float4 p4 = *(const float4*)(row + kbase);
            p0 = p4.x; p1 = p4.y; p2 = p4.z; p3 = p4.w;
        } else {
            p0 = row[0]; p1 = row[1]; p2 = row[2]; p3 = row[2047];
        }
        float e0 = __expf(ln0 - betaf * p0);
        float e1 = __expf(ln1 - betaf * p1);
        float e2 = __expf(ln2 - betaf * p2);
        float e3 = __expf(ln3 - betaf * p3);
        double s = (double)((e0 + e1) + (e2 + e3));
#pragma unroll
        for (int off = 1; off < 64; off <<= 1) s += __shfl_xor(s, off, 64);
        if (l == 0) wred[w] = s;
        __syncthreads();
        double ss = ((wred[0] + wred[1]) + (wred[2] + wred[3]))
                  + ((wred[4] + wred[5]) + (wred[6] + wred[7]));
        float gf = (float)(-log(ss));
        __syncthreads();
        acc.x += __expf(gf - betaf * p0);
        acc.y += __expf(gf - betaf * p1);
        acc.z += __expf(gf - betaf * p2);
        acc.w += __expf(gf - betaf * p3);
    }
    // slot layout: t<511 -> slots 4t..4t+3 (k=3+4t..); t=511 -> slots 2044..2047 (k=0,1,2,2047)
    ((float4*)(part + (long)blockIdx.x * K_N))[t] = acc;
}

// reduce fused partials -> lnr (wave per k, deterministic)
__global__ __launch_bounds__(512) void k_freduce(const float* __restrict__ part,
                                                 double* __restrict__ lnr64,
                                                 float* __restrict__ lnrf) {
    int t = threadIdx.x, l = t & 63, w = t >> 6;
    int k = blockIdx.x * 8 + w;
    int slot = (k >= 3 && k < 2047) ? (k - 3) : (k < 3 ? 2044 + k : 2047);
    double s = 0.0;
#pragma unroll
    for (int j = 0; j < 8; ++j)
        s += (double)part[(long)(l + 64 * j) * K_N + slot];
#pragma unroll
    for (int off = 1; off < 64; off <<= 1) s += __shfl_xor(s, off, 64);
    if (l == 0) { double v = -log(s); lnr64[k] = v; lnrf[k] = (float)v; }
}

// ---------------- final: wave per row — hoisted loads, argmax(f64), dc in place,
// loss via ||e-x||^2 = A64[b] + P[b,bi] (P recovered from dec), gather emb ----------------
__global__ __launch_bounds__(512) void k_final(const double* __restrict__ lnr64,
                                               const double* __restrict__ sc,
                                               const double* __restrict__ A64,
                                               const float* __restrict__ emb,
                                               float* __restrict__ out,
                                               double* __restrict__ lossp) {
    int t = threadIdx.x, l = t & 63, w = t >> 6;
    long b = (long)blockIdx.x * 8 + w;
    float* row = out + OUT_DC + b * K_N;     // P in, dc out (disjoint per wave)
    double beta = sc[3], mid = sc[0], inva = 1.0 / sc[1];
    double a64b = A64[b];
    // ---- hoist ALL loads before any store (avoid alias serialization) ----
    float pe = 0.f;
    if (l < 3)   pe = row[l];
    if (l == 63) pe = row[2047];
    float4 pv[8];
#pragma unroll
    for (int c = 0; c < 8; ++c) {
        int i = l + 64 * c;
        if (i < 511) pv[c] = *(const float4*)(row + 3 + 4 * i);
    }
    // ---- argmax (in-lane ascending k -> first-max) + dc stores ----
    double best = -1e300; int bi = 1 << 30;
    if (l < 3) {
        double p = (double)pe;
        double dec = lnr64[l] - beta * p;
        if (dec > best) { best = dec; bi = l; }
        row[l] = (float)((a64b + p - mid) * inva);
    }
#pragma unroll
    for (int c = 0; c < 8; ++c) {
        int i = l + 64 * c;
        if (i < 511) {
            int k = 3 + 4 * i;
            double p0 = pv[c].x, p1 = pv[c].y, p2 = pv[c].z, p3 = pv[c].w;
            double d0 = lnr64[k] - beta * p0;
            double d1 = lnr64[k + 1] - beta * p1;
            double d2 = lnr64[k + 2] - beta * p2;
            double d3 = lnr64[k + 3] - beta * p3;
            if (d0 > best) { best = d0; bi = k; }
            if (d1 > best) { best = d1; bi = k + 1; }
            if (d2 > best) { best = d2; bi = k + 2; }
            if (d3 > best) { best = d3; bi = k + 3; }
            float4 dcv;
            dcv.x = (float)((a64b + p0 - mid) * inva);
            dcv.y = (float)((a64b + p1 - mid) * inva);
            dcv.z = (float)((a64b + p2 - mid) * inva);
            dcv.w = (float)((a64b + p3 - mid) * inva);
            *(float4*)(row + k) = dcv;
        }
    }
    if (l == 63) {
        double p = (double)pe;
        double dec = lnr64[2047] - beta * p;
        if (dec > best) { best = dec; bi = 2047; }
        row[2047] = (float)((a64b + p - mid) * inva);
    }
#pragma unroll
    for (int off = 1; off < 64; off <<= 1) {                   // first-max: min idx on ties
        double ov = __shfl_xor(best, off, 64);
        int oi = __shfl_xor(bi, off, 64);
        if (ov > best || (ov == best && oi < bi)) { best = ov; bi = oi; }
    }
    if (l == 0) {
        out[OUT_IDX + b] = (float)bi;
        // ||e_bi - x_b||^2 = A64[b] + P[b,bi]; P recovered: dec = lnr - beta*P
        double prec = (lnr64[bi] - best) / beta;
        lossp[b] = a64b + prec;
    }
    // gather emb -> x_q
    const float4* E4 = (const float4*)(emb + (long)bi * D_N);
    float4* O4 = (float4*)(out + OUT_XQ + b * D_N);
#pragma unroll
    for (int i = 0; i < 3; ++i) O4[i * 64 + l] = E4[i * 64 + l];
}

__global__ __launch_bounds__(1024) void k_loss2(const double* __restrict__ lossp,
                                                float* __restrict__ out) {
    __shared__ double red[1024];
    int t = threadIdx.x;
    double s = 0.0;
#pragma unroll
    for (int j = 0; j < 8; ++j) s += lossp[t + 1024 * j];
    red[t] = s; __syncthreads();
    for (int st = 512; st > 0; st >>= 1) { if (t < st) red[t] += red[t + st]; __syncthreads(); }
    if (t == 0) out[OUT_LOSS] = (float)(red[0] * 1.25 / (double)((long)B_N * D_N));
}

extern "C" void kernel_launch(void* const* d_in, const int* in_sizes, int n_in,
                              void* d_out, int out_size, void* d_ws, size_t ws_size,
                              hipStream_t stream) {
    const float* x  = (const float*)d_in[0];   // [8192,768]
    const float* Am = (const float*)d_in[1];   // [2048,32]
    const float* Bm = (const float*)d_in[2];   // [32,768]
    float* out = (float*)d_out;
    float* P = out + OUT_DC;                   // P lives in dc region; k_final converts in place

    char* ws = (char*)d_ws;
    float*  emb     = (float*)(ws);                 // 6,291,456 B
    // 4 MB pool at +6291456: y (1 MB, dead after pgemm) | cs_part (1 MB, dead after c0's
    // colsum2) | 2 MB spare — reused as fpart [512][2048] f32 by k_fused/k_freduce.
    // BT (96 KB) overlays the cs_part region: written by k_btr, dead after k_ygemm,
    // long before k_colsum first writes cs_part.
    float*  y       = (float*)(ws + 6291456);       // 1,048,576 B
    float*  cs_part = (float*)(ws + 7340032);       // 128*2048*4 = 1,048,576 B
    float*  BTg     = (float*)(ws + 7340032);       // 98,304 B (overlays cs_part)
    float*  fpart   = (float*)(ws + 6291456);       // 512*2048*4 = 4,194,304 B (overlays y+cs_part)
    double* A64     = (double*)(ws + 10485760);     // 65,536 B
    float*  hf      = (float*)(ws + 10551296);      // 8,192 B
    float*  gammaf  = (float*)(ws + 10559488);      // 32,768 B
    double* lnr64   = (double*)(ws + 10592256);     // 16,384 B
    float*  lnrf    = (float*)(ws + 10608640);      // 8,192 B
    double* mmpart  = (double*)(ws + 10616832);     // 2048*2*8 = 32,768 B
    double* sc      = (double*)(ws + 10649600);     // 4 doubles
    double* lossp   = (double*)(ws + 10649856);     // 8192*8 = 65,536 B
    // total ws use ~10.7 MB

    k_btr<<<96, 256, 0, stream>>>(Bm, BTg);
    k_emb<<<K_N, 256, 0, stream>>>(Am, Bm, emb, hf);
    k_ygemm<<<B_N / 8, 256, 0, stream>>>(x, BTg, y, A64);

    dim3 gp(K_N / 256, B_N / 32);
    k_pgemm<<<gp, 256, 0, stream>>>(Am, y, hf, A64, P, mmpart);
    k_minmax2<<<1, 256, 0, stream>>>(mmpart, sc, A64, gammaf, 2048);

    // c0 (colsum with gamma0), then 5 fused (rowsum_i + colsum_{i+1}) passes:
    // total colsum x6 / rowsum x5 == R4's schedule; contraction ~0.022/cycle,
    // residual ~2e-10 << ~1e-6 decision gap.
    dim3 ga(K_N / 256, 128);
    k_colsum<<<ga, 256, 0, stream>>>(P, gammaf, sc, cs_part);
    k_colsum2<<<K_N / 256, 256, 0, stream>>>(cs_part, lnr64, lnrf);
    for (int it = 0; it < 5; ++it) {
        k_fused<<<512, 512, 0, stream>>>(P, lnrf, sc, fpart);
        k_freduce<<<256, 512, 0, stream>>>(fpart, lnr64, lnrf);
    }

    k_final<<<B_N / 8, 512, 0, stream>>>(lnr64, sc, A64, emb, out, lossp);
    k_loss2<<<1, 1024, 0, stream>>>(lossp, out);
}

// Round 4
// 422.371 us; speedup vs baseline: 1.1023x; 1.0940x over previous
//
#include <hip/hip_runtime.h>
#include <math.h>

// Problem constants
#define B_N 8192
#define K_N 2048
#define D_N 768
#define R_N 32

// d_out element offsets: [x_q_st | loss | indices | dc]
#define OUT_XQ   0L
#define OUT_LOSS 6291456L
#define OUT_IDX  6291457L
#define OUT_DC   6299649L   // odd -> dc/P rows are 4B-aligned only; k==3 (mod 4) is 16B-aligned

// ---------------- emb = A @ B (f64 accumulate), h_k = ||e_k||^2  [bitwise == R4] ----------------
__global__ __launch_bounds__(256) void k_emb(const float* __restrict__ A,
                                             const float* __restrict__ Bm,
                                             float* __restrict__ emb,
                                             float* __restrict__ hf) {
    int k = blockIdx.x, t = threadIdx.x;
    __shared__ float a_s[R_N];
    if (t < R_N) a_s[t] = A[k * R_N + t];
    __syncthreads();
    double hpart = 0.0;
    for (int d = t; d < D_N; d += 256) {
        double e = 0.0;
#pragma unroll
        for (int r = 0; r < R_N; ++r) e += (double)a_s[r] * (double)Bm[r * D_N + d];
        float ef = (float)e;
        emb[(long)k * D_N + d] = ef;
        hpart += (double)ef * (double)ef;
    }
    __shared__ double red[256];
    red[t] = hpart; __syncthreads();
    for (int s = 128; s > 0; s >>= 1) { if (t < s) red[t] += red[t + s]; __syncthreads(); }
    if (t == 0) hf[k] = (float)red[0];
}

// ---------------- BT pack: BT4[i*32+r] = float4(B[r][4i..4i+3]) ----------------
__global__ __launch_bounds__(256) void k_btr(const float* __restrict__ Bm,
                                             float* __restrict__ BT) {
    int j = blockIdx.x * 256 + threadIdx.x;   // 192*32*4 = 24576 floats
    int i = j >> 7;                           // float4 index 0..191
    int rc = j & 127;
    int r = rc >> 2, c = rc & 3;
    BT[j] = Bm[r * D_N + 4 * i + c];
}

// ---------------- y = x @ B^T [bitwise == R4] + fused ||x_b||^2 (f64) ----------------
// R4 rework: BOTH operands through LDS (the only reliably-pipelined primitives here:
// global_load_lds staging + compiler-scheduled ds_read).
//   xs: 8-row x tile (24 KB), staged once.
//   bs: quarter of packed BT (24 KB), restaged 4x (phase loop). B stays L2/L3-hot.
//   LDS total ~50 KB -> 3 blocks/CU = 12 waves/CU; per step: 2 ds_read_b128 + 4 FMA.
//   No register pipeline (R2/R3 failure: compiler collapses it or spills; R3 WRITE_SIZE
//   19.7 MB was scratch). VGPR stays low by construction.
// Per-row FMA chain (i ascending, x/y/z/w, (x+y)+(z+w)) and norm order IDENTICAL to R4
// -> y and A64 bitwise unchanged.
__global__ __launch_bounds__(256) void k_ygemm(const float* __restrict__ x,
                                               const float* __restrict__ BT,
                                               float* __restrict__ y,
                                               double* __restrict__ A64) {
    __shared__ __align__(16) float xs[8 * D_N];      // 24 KB
    __shared__ __align__(16) float bs[48 * 128];     // 24 KB = quarter of BT (48 float4-chunks x 32 r)
    __shared__ double normred[8][32];
    int t = threadIdx.x;
    long b0 = (long)blockIdx.x * 8;
    int h = (t >> 5) & 1, r = t & 31, w = t >> 6;
    int row_local = 2 * w + h;                       // 0..7

    // ---- stage x tile (contiguous 24 KB) + B quarter 0, async global->LDS ----
    const float* xsrc = x + b0 * D_N;
#pragma unroll
    for (int j = 0; j < 6; ++j) {
        __builtin_amdgcn_global_load_lds(
            (const __attribute__((address_space(1))) void*)(xsrc + j * 1024 + t * 4),
            (__attribute__((address_space(3))) void*)(xs + j * 1024 + t * 4),
            16, 0, 0);
    }
#pragma unroll
    for (int j = 0; j < 6; ++j) {
        __builtin_amdgcn_global_load_lds(
            (const __attribute__((address_space(1))) void*)(BT + j * 1024 + t * 4),
            (__attribute__((address_space(3))) void*)(bs + j * 1024 + t * 4),
            16, 0, 0);
    }
    __syncthreads();   // drains vmcnt(0) before any LDS read

    const float4* xs4 = (const float4*)(xs + row_local * D_N);
    const float4* bs4 = (const float4*)bs;
    float4 acc = make_float4(0.f, 0.f, 0.f, 0.f);

#pragma unroll 1
    for (int p = 0; p < 4; ++p) {
        if (p > 0) {
            __syncthreads();   // previous compute done reading bs
#pragma unroll
            for (int j = 0; j < 6; ++j) {
                __builtin_amdgcn_global_load_lds(
                    (const __attribute__((address_space(1))) void*)(BT + p * 6144 + j * 1024 + t * 4),
                    (__attribute__((address_space(3))) void*)(bs + j * 1024 + t * 4),
                    16, 0, 0);
            }
            __syncthreads();   // drain staging
        }
#pragma unroll
        for (int i = 0; i < 48; ++i) {
            float4 bb = bs4[i * 32 + r];
            float4 xv = xs4[p * 48 + i];
            acc.x = fmaf(xv.x, bb.x, acc.x);
            acc.y = fmaf(xv.y, bb.y, acc.y);
            acc.z = fmaf(xv.z, bb.z, acc.z);
            acc.w = fmaf(xv.w, bb.w, acc.w);
        }
    }
    y[(b0 + row_local) * R_N + r] = (acc.x + acc.y) + (acc.z + acc.w);

    // xnorm partials from LDS (same bits as global x): (row,r) sums d = r+32q, q
    // ascending; then serial r2-ascending combine — chain order IDENTICAL to R4.
    const float* xr = xs + row_local * D_N + r;
    double nv = 0.0;
#pragma unroll
    for (int q = 0; q < 24; ++q) {
        double v = (double)xr[32 * q];
        nv += v * v;
    }
    normred[row_local][r] = nv;
    __syncthreads();
    if (t < 8) {
        double s = 0.0;
#pragma unroll
        for (int r2 = 0; r2 < 32; ++r2) s += normred[t][r2];
        A64[b0 + t] = s;
    }
}

// ---------------- P[b,k] = h_k - 2 y_b.A_k + fused min/max partials  [bitwise == R4] ----------------
__global__ __launch_bounds__(256) void k_pgemm(const float* __restrict__ Am,
                                               const float* __restrict__ y,
                                               const float* __restrict__ hf,
                                               const double* __restrict__ A64,
                                               float* __restrict__ P,
                                               double* __restrict__ mmpart) {
    __shared__ float As[256][33];
    __shared__ float ys[32][32];
    __shared__ double a64s[32];
    __shared__ double smn[256], smx[256];
    int t = threadIdx.x;
    int k0 = blockIdx.x * 256, b0 = blockIdx.y * 32;
    for (int i = t; i < 256 * 32; i += 256) As[i >> 5][i & 31] = Am[(long)(k0 + (i >> 5)) * R_N + (i & 31)];
    for (int i = t; i < 32 * 32; i += 256) ys[i >> 5][i & 31] = y[(long)(b0 + (i >> 5)) * R_N + (i & 31)];
    if (t < 32) a64s[t] = A64[b0 + t];
    __syncthreads();
    int k = k0 + t;
    float ar[32];
#pragma unroll
    for (int r = 0; r < 32; ++r) ar[r] = As[t][r];
    float hk = hf[k];
    double mn = 1e300, mx = -1e300;
#pragma unroll 4
    for (int b = 0; b < 32; ++b) {
        float dot = 0.f;
#pragma unroll
        for (int r = 0; r < 32; ++r) dot = fmaf(ys[b][r], ar[r], dot);
        float p = fmaf(-2.f, dot, hk);
        P[(long)(b0 + b) * K_N + k] = p;
        double dv = a64s[b] + (double)p;
        mn = fmin(mn, dv); mx = fmax(mx, dv);
    }
    smn[t] = mn; smx[t] = mx; __syncthreads();
    for (int s = 128; s > 0; s >>= 1) {
        if (t < s) { smn[t] = fmin(smn[t], smn[t + s]); smx[t] = fmax(smx[t], smx[t + s]); }
        __syncthreads();
    }
    if (t == 0) {
        int bid = blockIdx.y * gridDim.x + blockIdx.x;
        mmpart[2 * bid] = smn[0]; mmpart[2 * bid + 1] = smx[0];
    }
}

// ---------------- minmax reduce -> sc, fused gamma init  [== R4] ----------------
__global__ __launch_bounds__(256) void k_minmax2(const double* __restrict__ part,
                                                 double* __restrict__ sc,
                                                 const double* __restrict__ A64,
                                                 float* __restrict__ gammaf, int nblk) {
    int t = threadIdx.x;
    double mn = 1e300, mx = -1e300;
    for (int i = t; i < nblk; i += 256) {
        mn = fmin(mn, part[2 * i]); mx = fmax(mx, part[2 * i + 1]);
    }
    __shared__ double smn[256], smx[256];
    __shared__ double ssc[4];
    smn[t] = mn; smx[t] = mx; __syncthreads();
    for (int s = 128; s > 0; s >>= 1) {
        if (t < s) { smn[t] = fmin(smn[t], smn[t + s]); smx[t] = fmax(smx[t], smx[t + s]); }
        __syncthreads();
    }
    if (t == 0) {
        double mid = (smx[0] + smn[0]) * 0.5;
        double ampl = smx[0] - mid + 1e-5;
        sc[0] = ssc[0] = mid; sc[1] = ssc[1] = ampl; sc[2] = ssc[2] = smn[0];
        sc[3] = ssc[3] = 1.0 / (0.01 * ampl);   // beta
    }
    __syncthreads();
    double bet = ssc[3], mnv = ssc[2];
    for (int i = t; i < B_N; i += 256)
        gammaf[i] = (float)(bet * (mnv - A64[i]));
}

// ---------------- first colsum (c0)  [bitwise == R4] ----------------
__global__ __launch_bounds__(256) void k_colsum(const float* __restrict__ P,
                                                const float* __restrict__ gammaf,
                                                const double* __restrict__ sc,
                                                float* __restrict__ part) {
    __shared__ float gs[64];
    int t = threadIdx.x;
    int k = blockIdx.x * 256 + t;
    int b0 = blockIdx.y * 64;
    if (t < 64) gs[t] = gammaf[b0 + t];
    __syncthreads();
    float betaf = (float)sc[3];
    float s0 = 0.f, s1 = 0.f, s2 = 0.f, s3 = 0.f;
#pragma unroll
    for (int j = 0; j < 64; j += 4) {
        s0 += __expf(gs[j]     - betaf * P[(long)(b0 + j)     * K_N + k]);
        s1 += __expf(gs[j + 1] - betaf * P[(long)(b0 + j + 1) * K_N + k]);
        s2 += __expf(gs[j + 2] - betaf * P[(long)(b0 + j + 2) * K_N + k]);
        s3 += __expf(gs[j + 3] - betaf * P[(long)(b0 + j + 3) * K_N + k]);
    }
    part[(long)blockIdx.y * K_N + k] = (s0 + s1) + (s2 + s3);
}

__global__ __launch_bounds__(256) void k_colsum2(const float* __restrict__ part,
                                                 double* __restrict__ lnr64,
                                                 float* __restrict__ lnrf) {
    int k = blockIdx.x * 256 + threadIdx.x;
    double s = 0.0;
#pragma unroll 4
    for (int c = 0; c < 128; ++c) s += (double)part[(long)c * K_N + k];
    double l = -log(s);
    lnr64[k] = l; lnrf[k] = (float)l;
}

// ---------------- fused rowsum_i + colsum_{i+1}: ONE pass over P ----------------
__global__ __launch_bounds__(512) void k_fused(const float* __restrict__ P,
                                               const float* __restrict__ lnrf,
                                               const double* __restrict__ sc,
                                               float* __restrict__ part) {
    __shared__ double wred[8];
    int t = threadIdx.x, l = t & 63, w = t >> 6;
    float betaf = (float)sc[3];
    int kbase = 3 + 4 * t;
    float ln0, ln1, ln2, ln3;
    if (t < 511) { ln0 = lnrf[kbase]; ln1 = lnrf[kbase + 1]; ln2 = lnrf[kbase + 2]; ln3 = lnrf[kbase + 3]; }
    else         { ln0 = lnrf[0];     ln1 = lnrf[1];         ln2 = lnrf[2];         ln3 = lnrf[2047]; }
    float4 acc = make_float4(0.f, 0.f, 0.f, 0.f);
    long rowbase = (long)blockIdx.x * 16;
    for (int rr = 0; rr < 16; ++rr) {
        const float* row = P + (rowbase + rr) * K_N;
        float p0, p1, p2, p3;
        if (t < 511) {
            float4 p4 = *(const float4*)(row + kbase);
            p0 = p4.x; p1 = p4.y; p2 = p4.z; p3 = p4.w;
        } else {
            p0 = row[0]; p1 = row[1]; p2 = row[2]; p3 = row[2047];
        }
        float e0 = __expf(ln0 - betaf * p0);
        float e1 = __expf(ln1 - betaf * p1);
        float e2 = __expf(ln2 - betaf * p2);
        float e3 = __expf(ln3 - betaf * p3);
        double s = (double)((e0 + e1) + (e2 + e3));
#pragma unroll
        for (int off = 1; off < 64; off <<= 1) s += __shfl_xor(s, off, 64);
        if (l == 0) wred[w] = s;
        __syncthreads();
        double ss = ((wred[0] + wred[1]) + (wred[2] + wred[3]))
                  + ((wred[4] + wred[5]) + (wred[6] + wred[7]));
        float gf = (float)(-log(ss));
        __syncthreads();
        acc.x += __expf(gf - betaf * p0);
        acc.y += __expf(gf - betaf * p1);
        acc.z += __expf(gf - betaf * p2);
        acc.w += __expf(gf - betaf * p3);
    }
    // slot layout: t<511 -> slots 4t..4t+3 (k=3+4t..); t=511 -> slots 2044..2047 (k=0,1,2,2047)
    ((float4*)(part + (long)blockIdx.x * K_N))[t] = acc;
}

// reduce fused partials -> lnr (wave per k, deterministic)
__global__ __launch_bounds__(512) void k_freduce(const float* __restrict__ part,
                                                 double* __restrict__ lnr64,
                                                 float* __restrict__ lnrf) {
    int t = threadIdx.x, l = t & 63, w = t >> 6;
    int k = blockIdx.x * 8 + w;
    int slot = (k >= 3 && k < 2047) ? (k - 3) : (k < 3 ? 2044 + k : 2047);
    double s = 0.0;
#pragma unroll
    for (int j = 0; j < 8; ++j)
        s += (double)part[(long)(l + 64 * j) * K_N + slot];
#pragma unroll
    for (int off = 1; off < 64; off <<= 1) s += __shfl_xor(s, off, 64);
    if (l == 0) { double v = -log(s); lnr64[k] = v; lnrf[k] = (float)v; }
}

// ---------------- final: wave per row — hoisted loads, argmax(f64), dc in place,
// loss via ||e-x||^2 = A64[b] + P[b,bi] (P recovered from dec), gather emb ----------------
__global__ __launch_bounds__(512) void k_final(const double* __restrict__ lnr64,
                                               const double* __restrict__ sc,
                                               const double* __restrict__ A64,
                                               const float* __restrict__ emb,
                                               float* __restrict__ out,
                                               double* __restrict__ lossp) {
    int t = threadIdx.x, l = t & 63, w = t >> 6;
    long b = (long)blockIdx.x * 8 + w;
    float* row = out + OUT_DC + b * K_N;     // P in, dc out (disjoint per wave)
    double beta = sc[3], mid = sc[0], inva = 1.0 / sc[1];
    double a64b = A64[b];
    // ---- hoist ALL loads before any store (avoid alias serialization) ----
    float pe = 0.f;
    if (l < 3)   pe = row[l];
    if (l == 63) pe = row[2047];
    float4 pv[8];
#pragma unroll
    for (int c = 0; c < 8; ++c) {
        int i = l + 64 * c;
        if (i < 511) pv[c] = *(const float4*)(row + 3 + 4 * i);
    }
    // ---- argmax (in-lane ascending k -> first-max) + dc stores ----
    double best = -1e300; int bi = 1 << 30;
    if (l < 3) {
        double p = (double)pe;
        double dec = lnr64[l] - beta * p;
        if (dec > best) { best = dec; bi = l; }
        row[l] = (float)((a64b + p - mid) * inva);
    }
#pragma unroll
    for (int c = 0; c < 8; ++c) {
        int i = l + 64 * c;
        if (i < 511) {
            int k = 3 + 4 * i;
            double p0 = pv[c].x, p1 = pv[c].y, p2 = pv[c].z, p3 = pv[c].w;
            double d0 = lnr64[k] - beta * p0;
            double d1 = lnr64[k + 1] - beta * p1;
            double d2 = lnr64[k + 2] - beta * p2;
            double d3 = lnr64[k + 3] - beta * p3;
            if (d0 > best) { best = d0; bi = k; }
            if (d1 > best) { best = d1; bi = k + 1; }
            if (d2 > best) { best = d2; bi = k + 2; }
            if (d3 > best) { best = d3; bi = k + 3; }
            float4 dcv;
            dcv.x = (float)((a64b + p0 - mid) * inva);
            dcv.y = (float)((a64b + p1 - mid) * inva);
            dcv.z = (float)((a64b + p2 - mid) * inva);
            dcv.w = (float)((a64b + p3 - mid) * inva);
            *(float4*)(row + k) = dcv;
        }
    }
    if (l == 63) {
        double p = (double)pe;
        double dec = lnr64[2047] - beta * p;
        if (dec > best) { best = dec; bi = 2047; }
        row[2047] = (float)((a64b + p - mid) * inva);
    }
#pragma unroll
    for (int off = 1; off < 64; off <<= 1) {                   // first-max: min idx on ties
        double ov = __shfl_xor(best, off, 64);
        int oi = __shfl_xor(bi, off, 64);
        if (ov > best || (ov == best && oi < bi)) { best = ov; bi = oi; }
    }
    if (l == 0) {
        out[OUT_IDX + b] = (float)bi;
        // ||e_bi - x_b||^2 = A64[b] + P[b,bi]; P recovered: dec = lnr - beta*P
        double prec = (lnr64[bi] - best) / beta;
        lossp[b] = a64b + prec;
    }
    // gather emb -> x_q
    const float4* E4 = (const float4*)(emb + (long)bi * D_N);
    float4* O4 = (float4*)(out + OUT_XQ + b * D_N);
#pragma unroll
    for (int i = 0; i < 3; ++i) O4[i * 64 + l] = E4[i * 64 + l];
}

__global__ __launch_bounds__(1024) void k_loss2(const double* __restrict__ lossp,
                                                float* __restrict__ out) {
    __shared__ double red[1024];
    int t = threadIdx.x;
    double s = 0.0;
#pragma unroll
    for (int j = 0; j < 8; ++j) s += lossp[t + 1024 * j];
    red[t] = s; __syncthreads();
    for (int st = 512; st > 0; st >>= 1) { if (t < st) red[t] += red[t + st]; __syncthreads(); }
    if (t == 0) out[OUT_LOSS] = (float)(red[0] * 1.25 / (double)((long)B_N * D_N));
}

extern "C" void kernel_launch(void* const* d_in, const int* in_sizes, int n_in,
                              void* d_out, int out_size, void* d_ws, size_t ws_size,
                              hipStream_t stream) {
    const float* x  = (const float*)d_in[0];   // [8192,768]
    const float* Am = (const float*)d_in[1];   // [2048,32]
    const float* Bm = (const float*)d_in[2];   // [32,768]
    float* out = (float*)d_out;
    float* P = out + OUT_DC;                   // P lives in dc region; k_final converts in place

    char* ws = (char*)d_ws;
    float*  emb     = (float*)(ws);                 // 6,291,456 B
    // 4 MB pool at +6291456: y (1 MB, dead after pgemm) | cs_part (1 MB, dead after c0's
    // colsum2) | 2 MB spare — reused as fpart [512][2048] f32 by k_fused/k_freduce.
    // BT (96 KB) overlays the cs_part region: written by k_btr, dead after k_ygemm,
    // long before k_colsum first writes cs_part.
    float*  y       = (float*)(ws + 6291456);       // 1,048,576 B
    float*  cs_part = (float*)(ws + 7340032);       // 128*2048*4 = 1,048,576 B
    float*  BTg     = (float*)(ws + 7340032);       // 98,304 B (overlays cs_part)
    float*  fpart   = (float*)(ws + 6291456);       // 512*2048*4 = 4,194,304 B (overlays y+cs_part)
    double* A64     = (double*)(ws + 10485760);     // 65,536 B
    float*  hf      = (float*)(ws + 10551296);      // 8,192 B
    float*  gammaf  = (float*)(ws + 10559488);      // 32,768 B
    double* lnr64   = (double*)(ws + 10592256);     // 16,384 B
    float*  lnrf    = (float*)(ws + 10608640);      // 8,192 B
    double* mmpart  = (double*)(ws + 10616832);     // 2048*2*8 = 32,768 B
    double* sc      = (double*)(ws + 10649600);     // 4 doubles
    double* lossp   = (double*)(ws + 10649856);     // 8192*8 = 65,536 B
    // total ws use ~10.7 MB

    k_btr<<<96, 256, 0, stream>>>(Bm, BTg);
    k_emb<<<K_N, 256, 0, stream>>>(Am, Bm, emb, hf);
    k_ygemm<<<B_N / 8, 256, 0, stream>>>(x, BTg, y, A64);

    dim3 gp(K_N / 256, B_N / 32);
    k_pgemm<<<gp, 256, 0, stream>>>(Am, y, hf, A64, P, mmpart);
    k_minmax2<<<1, 256, 0, stream>>>(mmpart, sc, A64, gammaf, 2048);

    // c0 (colsum with gamma0), then 5 fused (rowsum_i + colsum_{i+1}) passes:
    // total colsum x6 / rowsum x5 == R4's schedule; contraction ~0.022/cycle,
    // residual ~2e-10 << ~1e-6 decision gap.
    dim3 ga(K_N / 256, 128);
    k_colsum<<<ga, 256, 0, stream>>>(P, gammaf, sc, cs_part);
    k_colsum2<<<K_N / 256, 256, 0, stream>>>(cs_part, lnr64, lnrf);
    for (int it = 0; it < 5; ++it) {
        k_fused<<<512, 512, 0, stream>>>(P, lnrf, sc, fpart);
        k_freduce<<<256, 512, 0, stream>>>(fpart, lnr64, lnrf);
    }

    k_final<<<B_N / 8, 512, 0, stream>>>(lnr64, sc, A64, emb, out, lossp);
    k_loss2<<<1, 1024, 0, stream>>>(lossp, out);
}